// Round 2
// baseline (1247.102 us; speedup 1.0000x reference)
//
#include <hip/hip_runtime.h>
#include <hip/hip_bf16.h>
#include <math.h>

using bf16 = __hip_bfloat16;
typedef __attribute__((ext_vector_type(8))) __bf16 bf16x8;
typedef __attribute__((ext_vector_type(4))) float f32x4;

__device__ __forceinline__ float b2f(bf16 x){ return __bfloat162float(x); }
__device__ __forceinline__ bf16  f2b(float x){ return __float2bfloat16(x); }
__device__ __forceinline__ float ldf(const float* p, size_t i){ return p[i]; }
__device__ __forceinline__ float ldf(const bf16*  p, size_t i){ return b2f(p[i]); }
__device__ __forceinline__ void stf(float* p, size_t i, float v){ p[i] = v; }
__device__ __forceinline__ void stf(bf16*  p, size_t i, float v){ p[i] = f2b(v); }

#define NHEAD 12
#define HDIM  64
#define HID   768
#define SEQ   512
#define BATCH 32
#define ROWS  (BATCH*SEQ)   // 16384
#define QCH   128           // q-chunk rows for attention
#define NCHUNK (SEQ/QCH)    // 4

// ---------------------------------------------------------------------------
// MFMA GEMM: C[M,N] = A[M,K] * Bt[N,K]^T (+bias +epilogue), batched over
// blockIdx.z (z1=z/zdiv, z2=z%zdiv offsets). A is fp32 or bf16 (cast during
// LDS staging). C is bf16. EPI: 0=bias, 1=bias+gelu(exact), 2=bias+residual.
// ---------------------------------------------------------------------------
template<int BM,int BN,int WM,int WN,int EPI,typename TA,typename TR>
__global__ __launch_bounds__(256)
void gemm_bt(const TA* __restrict__ A, int lda, long long sA1, long long sA2,
             const bf16* __restrict__ Bt, int ldb, long long sB1, long long sB2,
             bf16* __restrict__ C, int ldc, long long sC1, long long sC2,
             int K, int zdiv,
             const float* __restrict__ bias,
             const TR* __restrict__ res, int ldres)
{
  constexpr int BK = 32;
  constexpr int WCOLS = BN / WN;
  constexpr int MT = WM/16, NT = WN/16;
  const int z = blockIdx.z;
  const int z1 = z / zdiv, z2 = z - z1*zdiv;
  A  += (long long)z1*sA1 + (long long)z2*sA2;
  Bt += (long long)z1*sB1 + (long long)z2*sB2;
  C  += (long long)z1*sC1 + (long long)z2*sC2;

  const int m0 = blockIdx.y*BM, n0 = blockIdx.x*BN;
  __shared__ __align__(16) bf16 As[BM*BK];
  __shared__ __align__(16) bf16 Bs[BN*BK];

  const int tid  = threadIdx.x;
  const int wave = tid>>6, lane = tid&63;
  const int r = lane&15, qd = lane>>4;
  const int wr = wave / WCOLS, wc = wave - wr*WCOLS;

  f32x4 acc[MT][NT] = {};

  constexpr int ACH = BM*BK/8;   // 16B (8-elem) chunks in A tile
  constexpr int BCH = BN*BK/8;

  for (int k0=0;k0<K;k0+=BK){
    #pragma unroll
    for (int c0=0;c0<ACH;c0+=256){
      int c = c0 + tid;
      int row = c>>2, kc = c&3;
      if constexpr (sizeof(TA)==2) {
        ((uint4*)As)[c] = *(const uint4*)((const bf16*)A + (size_t)(m0+row)*lda + k0 + kc*8);
      } else {
        const float* Ap = (const float*)A + (size_t)(m0+row)*lda + k0 + kc*8;
        float4 f0 = *(const float4*)Ap;
        float4 f1 = *(const float4*)(Ap+4);
        union { uint4 u; __bf16 h[8]; } pk;
        pk.h[0]=(__bf16)f0.x; pk.h[1]=(__bf16)f0.y; pk.h[2]=(__bf16)f0.z; pk.h[3]=(__bf16)f0.w;
        pk.h[4]=(__bf16)f1.x; pk.h[5]=(__bf16)f1.y; pk.h[6]=(__bf16)f1.z; pk.h[7]=(__bf16)f1.w;
        ((uint4*)As)[c] = pk.u;
      }
    }
    #pragma unroll
    for (int c0=0;c0<BCH;c0+=256){
      int c = c0 + tid;
      int row = c>>2, kc = c&3;
      ((uint4*)Bs)[c] = *(const uint4*)(Bt + (size_t)(n0+row)*ldb + k0 + kc*8);
    }
    __syncthreads();
    bf16x8 af[MT]; bf16x8 bfr[NT];
    #pragma unroll
    for (int mi=0;mi<MT;mi++)
      af[mi] = *(const bf16x8*)(As + (wr*WM + mi*16 + r)*BK + qd*8);
    #pragma unroll
    for (int ni=0;ni<NT;ni++)
      bfr[ni] = *(const bf16x8*)(Bs + (wc*WN + ni*16 + r)*BK + qd*8);
    #pragma unroll
    for (int mi=0;mi<MT;mi++)
      #pragma unroll
      for (int ni=0;ni<NT;ni++)
        acc[mi][ni] = __builtin_amdgcn_mfma_f32_16x16x32_bf16(af[mi], bfr[ni], acc[mi][ni], 0,0,0);
    __syncthreads();
  }

  #pragma unroll
  for (int mi=0;mi<MT;mi++){
    #pragma unroll
    for (int ni=0;ni<NT;ni++){
      #pragma unroll
      for (int i=0;i<4;i++){
        int mm = m0 + wr*WM + mi*16 + qd*4 + i;   // C/D: row=(lane>>4)*4+i
        int nn = n0 + wc*WN + ni*16 + r;          //      col=lane&15
        float v = acc[mi][ni][i];
        if (bias) v += bias[nn];
        if (EPI==1) v = 0.5f*v*(1.0f + erff(v*0.70710678f));
        if (EPI==2) v += ldf(res, (size_t)mm*ldres + nn);
        C[(size_t)mm*ldc + nn] = f2b(v);
      }
    }
  }
}

// ---------------------------------------------------------------------------
// Weight transpose + fp32->bf16 cast: in fp32 [R][C] -> out bf16 [C][R]
// ---------------------------------------------------------------------------
__global__ void transpose_cast(const float* __restrict__ in, bf16* __restrict__ out,
                               int R, int C)
{
  __shared__ float tile[32][33];
  int bc = blockIdx.x*32, br = blockIdx.y*32;
  int tx = threadIdx.x, ty = threadIdx.y;
  #pragma unroll
  for (int i=ty;i<32;i+=8)
    tile[i][tx] = in[(size_t)(br+i)*C + bc+tx];
  __syncthreads();
  #pragma unroll
  for (int i=ty;i<32;i+=8)
    out[(size_t)(bc+i)*R + br+tx] = f2b(tile[tx][i]);
}

// V [b,s,h,d] (row stride 768, bf16) -> Vt [z=(b,h)][d][s]
__global__ void vtrans(const bf16* __restrict__ v, bf16* __restrict__ vt)
{
  int z = blockIdx.z; int b = z/NHEAD, h = z - b*NHEAD;
  int d0 = blockIdx.x*32, s0 = blockIdx.y*32;
  __shared__ bf16 t[32][33];
  int tx = threadIdx.x, ty = threadIdx.y;
  #pragma unroll
  for (int i=ty;i<32;i+=8)
    t[i][tx] = v[(size_t)(b*SEQ + s0+i)*HID + h*HDIM + d0+tx];
  __syncthreads();
  #pragma unroll
  for (int i=ty;i<32;i+=8)
    vt[(size_t)z*HDIM*SEQ + (size_t)(d0+i)*SEQ + s0+tx] = t[tx][i];
}

// ---------------------------------------------------------------------------
// softmax over 512 keys (scale 1/8 + additive fp32 mask), in-place
// grid: (QCH, B*NH)
// ---------------------------------------------------------------------------
__global__ __launch_bounds__(256)
void softmax512(bf16* __restrict__ sc, const float* __restrict__ mask)
{
  int z = blockIdx.y; int b = z / NHEAD;
  bf16* row = sc + ((size_t)z*QCH + blockIdx.x)*SEQ;
  int t = threadIdx.x;
  float v0 = b2f(row[t      ])*0.125f + mask[b*SEQ + t      ];
  float v1 = b2f(row[t + 256])*0.125f + mask[b*SEQ + t + 256];
  float m = fmaxf(v0, v1);
  #pragma unroll
  for (int off=32; off; off>>=1) m = fmaxf(m, __shfl_xor(m, off));
  __shared__ float redm[4], reds[4];
  int wv = t>>6, ln = t&63;
  if (ln==0) redm[wv] = m;
  __syncthreads();
  m = fmaxf(fmaxf(redm[0],redm[1]), fmaxf(redm[2],redm[3]));
  float e0 = __expf(v0-m), e1 = __expf(v1-m);
  float s = e0+e1;
  #pragma unroll
  for (int off=32; off; off>>=1) s += __shfl_xor(s, off);
  if (ln==0) reds[wv] = s;
  __syncthreads();
  s = reds[0]+reds[1]+reds[2]+reds[3];
  float inv = 1.0f/s;
  row[t      ] = f2b(e0*inv);
  row[t + 256] = f2b(e1*inv);
}

// ---------------------------------------------------------------------------
// LayerNorm over 768 cols, one block per row. In-place-safe (dst may == y).
// ---------------------------------------------------------------------------
template<typename TO>
__global__ __launch_bounds__(256)
void ln768(const bf16* __restrict__ y, const float* __restrict__ g,
           const float* __restrict__ be, TO* __restrict__ dst)
{
  size_t row = blockIdx.x;
  const bf16* yr = y + row*HID;
  int t = threadIdx.x;
  float x0 = b2f(yr[t]), x1 = b2f(yr[t+256]), x2 = b2f(yr[t+512]);
  float s = x0+x1+x2, q = x0*x0+x1*x1+x2*x2;
  #pragma unroll
  for (int off=32; off; off>>=1){ s += __shfl_xor(s, off); q += __shfl_xor(q, off); }
  __shared__ float rs[4], rq[4];
  int wv = t>>6;
  if ((t&63)==0){ rs[wv]=s; rq[wv]=q; }
  __syncthreads();
  s = rs[0]+rs[1]+rs[2]+rs[3];
  q = rq[0]+rq[1]+rq[2]+rq[3];
  float mean = s*(1.0f/HID);
  float var  = q*(1.0f/HID) - mean*mean;
  float inv  = rsqrtf(var + 1e-12f);
  TO* dr = dst + row*HID;
  stf(dr, t,     (x0-mean)*inv*g[t    ] + be[t    ]);
  stf(dr, t+256, (x1-mean)*inv*g[t+256] + be[t+256]);
  stf(dr, t+512, (x2-mean)*inv*g[t+512] + be[t+512]);
}

// ---------------------------------------------------------------------------
// Dialog (CLS) block: 32 rows total — scalar kernels, fp32 weights
// ---------------------------------------------------------------------------
__global__ __launch_bounds__(256)
void cls_proj(const bf16* __restrict__ x2,
              const float* __restrict__ Wq, const float* __restrict__ bq,
              const float* __restrict__ Wk, const float* __restrict__ bk,
              const float* __restrict__ Wv, const float* __restrict__ bv,
              bf16* __restrict__ oq, bf16* __restrict__ ok, bf16* __restrict__ ov)
{
  int mat = blockIdx.x, row = blockIdx.y;
  const float* W  = mat==0 ? Wq : (mat==1 ? Wk : Wv);
  const float* bi = mat==0 ? bq : (mat==1 ? bk : bv);
  bf16* out       = mat==0 ? oq : (mat==1 ? ok : ov);
  __shared__ float a[HID];
  const bf16* xr = x2 + (size_t)row*SEQ*HID;    // cls token of batch `row`
  for (int i=threadIdx.x;i<HID;i+=256) a[i] = b2f(xr[i]);
  __syncthreads();
  for (int c0=0;c0<HID;c0+=256){
    int col = c0 + threadIdx.x;
    float acc = 0.f;
    for (int k=0;k<HID;k++) acc += a[k]*W[(size_t)k*HID + col];
    out[(size_t)row*HID + col] = f2b(acc + bi[col]);
  }
}

// grid 48 = (4 dialog-batches x 12 heads), block 64
__global__ __launch_bounds__(64)
void cls_attn(const bf16* __restrict__ q, const bf16* __restrict__ k,
              const bf16* __restrict__ v, bf16* __restrict__ ctx)
{
  int z = blockIdx.x; int bb = z/NHEAD, h = z - bb*NHEAD;
  __shared__ float P[8][8];
  int t = threadIdx.x;
  int qi = t>>3, ki = t&7;
  float s = 0.f;
  for (int d=0; d<HDIM; d++)
    s += b2f(q[(size_t)(bb*8+qi)*HID + h*HDIM + d]) *
         b2f(k[(size_t)(bb*8+ki)*HID + h*HDIM + d]);
  s = s*0.125f + (ki >= qi ? -10000.0f : 0.0f);   // mask: (k>=q)*-1e4
  float m = s;
  #pragma unroll
  for (int off=4; off; off>>=1) m = fmaxf(m, __shfl_xor(m, off, 8));
  float e = __expf(s - m);
  float sum = e;
  #pragma unroll
  for (int off=4; off; off>>=1) sum += __shfl_xor(sum, off, 8);
  P[qi][ki] = e/sum;
  __syncthreads();
  for (int q2=0; q2<8; q2++){
    float acc = 0.f;
    #pragma unroll
    for (int k2=0; k2<8; k2++)
      acc += P[q2][k2] * b2f(v[(size_t)(bb*8+k2)*HID + h*HDIM + t]);
    ctx[(size_t)(bb*8+q2)*HID + h*HDIM + t] = f2b(acc);
  }
}

// grid 32 rows: out-proj + bias + residual + LN, updates x2 cls rows in place
__global__ __launch_bounds__(256)
void cls_out(const bf16* __restrict__ ctx, const float* __restrict__ Wo,
             const float* __restrict__ bo, const float* __restrict__ g,
             const float* __restrict__ be, bf16* __restrict__ x2)
{
  int row = blockIdx.x;
  __shared__ float a[HID];
  __shared__ float yrow[HID];
  const bf16* cr = ctx + (size_t)row*HID;
  bf16* xr = x2 + (size_t)row*SEQ*HID;
  for (int i=threadIdx.x;i<HID;i+=256) a[i] = b2f(cr[i]);
  __syncthreads();
  for (int c0=0;c0<HID;c0+=256){
    int col = c0 + threadIdx.x;
    float acc = 0.f;
    for (int k=0;k<HID;k++) acc += a[k]*Wo[(size_t)k*HID + col];
    yrow[col] = acc + bo[col] + b2f(xr[col]);
  }
  __syncthreads();
  int t = threadIdx.x;
  float x0 = yrow[t], x1 = yrow[t+256], x2v = yrow[t+512];
  float s = x0+x1+x2v, qq = x0*x0+x1*x1+x2v*x2v;
  #pragma unroll
  for (int off=32; off; off>>=1){ s += __shfl_xor(s, off); qq += __shfl_xor(qq, off); }
  __shared__ float rs[4], rq[4];
  int wv = t>>6;
  if ((t&63)==0){ rs[wv]=s; rq[wv]=qq; }
  __syncthreads();
  s = rs[0]+rs[1]+rs[2]+rs[3];
  qq = rq[0]+rq[1]+rq[2]+rq[3];
  float mean = s*(1.0f/HID);
  float var  = qq*(1.0f/HID) - mean*mean;
  float inv  = rsqrtf(var + 1e-12f);
  xr[t    ] = f2b((x0 -mean)*inv*g[t    ] + be[t    ]);
  xr[t+256] = f2b((x1 -mean)*inv*g[t+256] + be[t+256]);
  xr[t+512] = f2b((x2v-mean)*inv*g[t+512] + be[t+512]);
}

// ---------------------------------------------------------------------------
extern "C" void kernel_launch(void* const* d_in, const int* in_sizes, int n_in,
                              void* d_out, int out_size, void* d_ws, size_t ws_size,
                              hipStream_t stream)
{
  const float* X    = (const float*)d_in[0];
  const float* AM   = (const float*)d_in[1];
  const float* Wq   = (const float*)d_in[2];  const float* bq  = (const float*)d_in[3];
  const float* Wk   = (const float*)d_in[4];  const float* bk  = (const float*)d_in[5];
  const float* Wv   = (const float*)d_in[6];  const float* bv  = (const float*)d_in[7];
  const float* Wao  = (const float*)d_in[8];  const float* bao = (const float*)d_in[9];
  const float* ln1g = (const float*)d_in[10]; const float* ln1b= (const float*)d_in[11];
  const float* dWq  = (const float*)d_in[12]; const float* dbq = (const float*)d_in[13];
  const float* dWk  = (const float*)d_in[14]; const float* dbk = (const float*)d_in[15];
  const float* dWv  = (const float*)d_in[16]; const float* dbv = (const float*)d_in[17];
  const float* dWo  = (const float*)d_in[18]; const float* dbo = (const float*)d_in[19];
  const float* dlng = (const float*)d_in[20]; const float* dlnb= (const float*)d_in[21];
  const float* Wi   = (const float*)d_in[22]; const float* bi  = (const float*)d_in[23];
  const float* Wo2  = (const float*)d_in[24]; const float* bo2 = (const float*)d_in[25];
  const float* ln2g = (const float*)d_in[26]; const float* ln2b= (const float*)d_in[27];
  float* OUT = (float*)d_out;

  // workspace layout (bf16 slabs, 256B-aligned). Peak ≈ 182 MiB.
  char* wp = (char*)d_ws;
  auto alloc = [&](size_t elems)->bf16*{
    bf16* p = (bf16*)wp;
    wp += ((elems*sizeof(bf16) + 255)/256)*256;
    return p;
  };
  bf16* wtq  = alloc(768*768);
  bf16* wtk  = alloc(768*768);
  bf16* wtv  = alloc(768*768);
  bf16* wtao = alloc(768*768);
  bf16* wti  = alloc((size_t)768*3072);
  bf16* wto2 = alloc((size_t)3072*768);
  bf16* qb   = alloc((size_t)ROWS*HID);          // } contiguous: inter aliases
  bf16* kb   = alloc((size_t)ROWS*HID);          // } qb..vtb (ROWS x 3072)
  bf16* vb   = alloc((size_t)ROWS*HID);
  bf16* vtb  = alloc((size_t)ROWS*HID);
  bf16* inter = qb;
  bf16* scb  = alloc((size_t)BATCH*NHEAD*QCH*SEQ); // 48 MiB slab, also yb/x2
  bf16* yb   = scb;   // out-proj output (sc dead), LN1 in-place, final out
  bf16* x2   = scb;   // post-LN1 activations (same slab; element-wise safe)
  bf16* ctxb = alloc((size_t)ROWS*HID);
  bf16* clsq = alloc(32*HID);
  bf16* clsk = alloc(32*HID);
  bf16* clsv = alloc(32*HID);
  bf16* clsc = alloc(32*HID);

  dim3 T32(32,8);
  // weight transpose+cast: W[K][N] fp32 -> Wt[N][K] bf16
  transpose_cast<<<dim3(24,24), T32, 0, stream>>>(Wq,  wtq, 768, 768);
  transpose_cast<<<dim3(24,24), T32, 0, stream>>>(Wk,  wtk, 768, 768);
  transpose_cast<<<dim3(24,24), T32, 0, stream>>>(Wv,  wtv, 768, 768);
  transpose_cast<<<dim3(24,24), T32, 0, stream>>>(Wao, wtao,768, 768);
  transpose_cast<<<dim3(96,24), T32, 0, stream>>>(Wi,  wti, 768, 3072);
  transpose_cast<<<dim3(24,96), T32, 0, stream>>>(Wo2, wto2,3072, 768);

  // QKV projections: [16384,768] @ [768,768], A read fp32 + cast in staging
  gemm_bt<128,128,64,64,0,float,float><<<dim3(6,128,1),256,0,stream>>>(
      X,768,0,0,  wtq,768,0,0,  qb,768,0,0,  768,1, bq, nullptr,0);
  gemm_bt<128,128,64,64,0,float,float><<<dim3(6,128,1),256,0,stream>>>(
      X,768,0,0,  wtk,768,0,0,  kb,768,0,0,  768,1, bk, nullptr,0);
  gemm_bt<128,128,64,64,0,float,float><<<dim3(6,128,1),256,0,stream>>>(
      X,768,0,0,  wtv,768,0,0,  vb,768,0,0,  768,1, bv, nullptr,0);

  vtrans<<<dim3(2,16,BATCH*NHEAD), T32, 0, stream>>>(vb, vtb);

  // attention in 4 q-chunks of 128 rows
  for (int c=0;c<NCHUNK;c++){
    gemm_bt<128,128,64,64,0,bf16,float><<<dim3(4,1,BATCH*NHEAD),256,0,stream>>>(
        qb + (size_t)c*QCH*HID, HID, (long long)SEQ*HID, HDIM,
        kb,                     HID, (long long)SEQ*HID, HDIM,
        scb, SEQ, (long long)NHEAD*QCH*SEQ, (long long)QCH*SEQ,
        HDIM, NHEAD, nullptr, nullptr, 0);
    softmax512<<<dim3(QCH, BATCH*NHEAD),256,0,stream>>>(scb, AM);
    gemm_bt<128,64,32,64,0,bf16,float><<<dim3(1,1,BATCH*NHEAD),256,0,stream>>>(
        scb, SEQ, (long long)NHEAD*QCH*SEQ, (long long)QCH*SEQ,
        vtb, SEQ, (long long)NHEAD*HDIM*SEQ, (long long)HDIM*SEQ,
        ctxb + (size_t)c*QCH*HID, HID, (long long)SEQ*HID, HDIM,
        SEQ, NHEAD, nullptr, nullptr, 0);
  }

  // attn out-proj + bias + residual(X fp32) -> yb ; LN1 in place -> x2
  gemm_bt<128,128,64,64,2,bf16,float><<<dim3(6,128,1),256,0,stream>>>(
      ctxb,768,0,0,  wtao,768,0,0,  yb,768,0,0,  768,1, bao, X, 768);
  ln768<bf16><<<ROWS,256,0,stream>>>(yb, ln1g, ln1b, x2);

  // dialog (CLS) block on 32 rows
  cls_proj<<<dim3(3,32),256,0,stream>>>(x2, dWq,dbq, dWk,dbk, dWv,dbv,
                                        clsq, clsk, clsv);
  cls_attn<<<48,64,0,stream>>>(clsq, clsk, clsv, clsc);
  cls_out<<<32,256,0,stream>>>(clsc, dWo, dbo, dlng, dlnb, x2);

  // FFN: inter = gelu(x2 @ Wi + bi)  [16384,3072]
  gemm_bt<128,128,64,64,1,bf16,float><<<dim3(24,128,1),256,0,stream>>>(
      x2,768,0,0,  wti,768,0,0,  inter,3072,0,0,  768,1, bi, nullptr,0);
  // y = inter @ Wo2 + bo2 + x2 (res==C slab: element-wise read-before-write)
  gemm_bt<128,128,64,64,2,bf16,bf16><<<dim3(6,128,1),256,0,stream>>>(
      inter,3072,0,0,  wto2,3072,0,0,  yb,768,0,0,  3072,1, bo2, x2, 768);
  ln768<float><<<ROWS,256,0,stream>>>(yb, ln2g, ln2b, OUT);
}

// Round 3
// 1188.203 us; speedup vs baseline: 1.0496x; 1.0496x over previous
//
#include <hip/hip_runtime.h>
#include <hip/hip_bf16.h>
#include <math.h>

using bf16 = __hip_bfloat16;
typedef __attribute__((ext_vector_type(8))) __bf16 bf16x8;
typedef __attribute__((ext_vector_type(4))) float f32x4;

__device__ __forceinline__ float b2f(bf16 x){ return __bfloat162float(x); }
__device__ __forceinline__ bf16  f2b(float x){ return __float2bfloat16(x); }
__device__ __forceinline__ float us2f(unsigned short u){ return __uint_as_float(((unsigned int)u)<<16); }
__device__ __forceinline__ float ldf(const float* p, size_t i){ return p[i]; }
__device__ __forceinline__ float ldf(const bf16*  p, size_t i){ return b2f(p[i]); }
__device__ __forceinline__ void stf(float* p, size_t i, float v){ p[i] = v; }
__device__ __forceinline__ void stf(bf16*  p, size_t i, float v){ p[i] = f2b(v); }

// async 16B global->LDS (wave-uniform LDS base + lane*16)
typedef const __attribute__((address_space(1))) unsigned int* gas_u32p;
typedef __attribute__((address_space(3))) unsigned int* las_u32p;
__device__ __forceinline__ void gl_lds16(const bf16* g, bf16* l){
  __builtin_amdgcn_global_load_lds((gas_u32p)(const void*)g, (las_u32p)(void*)l, 16, 0, 0);
}

#define NHEAD 12
#define HDIM  64
#define HID   768
#define SEQ   512
#define BATCH 32
#define ROWS  (BATCH*SEQ)   // 16384
#define QKVW  2304          // packed qkv row width
#define QCH   128           // q-chunk rows for attention
#define NCHUNK (SEQ/QCH)    // 4

// ---------------------------------------------------------------------------
// MFMA GEMM: C[M,N] = A[M,K] * Bt[N,K]^T (+bias +epilogue), batched over
// blockIdx.z (z1=z/zdiv, z2=z%zdiv). All operands bf16; fp32 accumulate.
// Staging via global_load_lds(16B) with XOR bank swizzle.
// EPI: 0=bias, 1=bias+gelu(exact), 2=bias+residual.
// ---------------------------------------------------------------------------
template<int BM,int BN,int WM,int WN,int EPI,typename TR>
__global__ __launch_bounds__(256)
void gemm_bt(const bf16* __restrict__ A, int lda, long long sA1, long long sA2,
             const bf16* __restrict__ Bt, int ldb, long long sB1, long long sB2,
             bf16* __restrict__ C, int ldc, long long sC1, long long sC2,
             int K, int zdiv,
             const float* __restrict__ bias,
             const TR* __restrict__ res, int ldres)
{
  constexpr int BK = 32;
  constexpr int WCOLS = BN / WN;
  constexpr int MT = WM/16, NT = WN/16;
  const int z = blockIdx.z;
  const int z1 = z / zdiv, z2 = z - z1*zdiv;
  A  += (long long)z1*sA1 + (long long)z2*sA2;
  Bt += (long long)z1*sB1 + (long long)z2*sB2;
  C  += (long long)z1*sC1 + (long long)z2*sC2;

  const int m0 = blockIdx.y*BM, n0 = blockIdx.x*BN;
  __shared__ __align__(16) bf16 As[BM*BK];
  __shared__ __align__(16) bf16 Bs[BN*BK];

  const int tid  = threadIdx.x;
  const int wave = tid>>6, lane = tid&63;
  const int r = lane&15, qd = lane>>4;
  const int wr = wave / WCOLS, wc = wave - wr*WCOLS;
  // swizzled k-column for LDS reads (store side permutes global source)
  const int kcol = (qd ^ ((r>>1)&3)) * 8;

  f32x4 acc[MT][NT] = {};

  constexpr int ACH = BM*BK/8;   // 16B chunks in A tile
  constexpr int BCH = BN*BK/8;

  for (int k0=0;k0<K;k0+=BK){
    #pragma unroll
    for (int c0=0;c0<ACH;c0+=256){
      int c = c0 + tid;
      int row = c>>2;
      int kc  = (c&3) ^ ((c>>3)&3);          // XOR swizzle (store side)
      gl_lds16(A + (size_t)(m0+row)*lda + k0 + kc*8,
               As + ((size_t)c0 + (size_t)wave*64)*8);
    }
    #pragma unroll
    for (int c0=0;c0<BCH;c0+=256){
      int c = c0 + tid;
      int row = c>>2;
      int kc  = (c&3) ^ ((c>>3)&3);
      gl_lds16(Bt + (size_t)(n0+row)*ldb + k0 + kc*8,
               Bs + ((size_t)c0 + (size_t)wave*64)*8);
    }
    __syncthreads();
    bf16x8 af[MT]; bf16x8 bfr[NT];
    #pragma unroll
    for (int mi=0;mi<MT;mi++)
      af[mi] = *(const bf16x8*)(As + (wr*WM + mi*16 + r)*BK + kcol);
    #pragma unroll
    for (int ni=0;ni<NT;ni++)
      bfr[ni] = *(const bf16x8*)(Bs + (wc*WN + ni*16 + r)*BK + kcol);
    #pragma unroll
    for (int mi=0;mi<MT;mi++)
      #pragma unroll
      for (int ni=0;ni<NT;ni++)
        acc[mi][ni] = __builtin_amdgcn_mfma_f32_16x16x32_bf16(af[mi], bfr[ni], acc[mi][ni], 0,0,0);
    __syncthreads();
  }

  #pragma unroll
  for (int mi=0;mi<MT;mi++){
    #pragma unroll
    for (int ni=0;ni<NT;ni++){
      #pragma unroll
      for (int i=0;i<4;i++){
        int mm = m0 + wr*WM + mi*16 + qd*4 + i;   // C/D: row=(lane>>4)*4+i
        int nn = n0 + wc*WN + ni*16 + r;          //      col=lane&15
        float v = acc[mi][ni][i];
        if (bias) v += bias[nn];
        if (EPI==1) v = 0.5f*v*(1.0f + erff(v*0.70710678f));
        if (EPI==2) v += ldf(res, (size_t)mm*ldres + nn);
        C[(size_t)mm*ldc + nn] = f2b(v);
      }
    }
  }
}

// ---------------------------------------------------------------------------
// Weight transpose + fp32->bf16 cast: in fp32 [R][C] -> out bf16 [C][R]
// ---------------------------------------------------------------------------
__global__ void transpose_cast(const float* __restrict__ in, bf16* __restrict__ out,
                               int R, int C)
{
  __shared__ float tile[32][33];
  int bc = blockIdx.x*32, br = blockIdx.y*32;
  int tx = threadIdx.x, ty = threadIdx.y;
  #pragma unroll
  for (int i=ty;i<32;i+=8)
    tile[i][tx] = in[(size_t)(br+i)*C + bc+tx];
  __syncthreads();
  #pragma unroll
  for (int i=ty;i<32;i+=8)
    out[(size_t)(bc+i)*R + br+tx] = f2b(tile[tx][i]);
}

// 4x 768x768 transposes in one launch (z picks matrix); dst contiguous slabs
__global__ void transpose_cast4(const float* __restrict__ w0, const float* __restrict__ w1,
                                const float* __restrict__ w2, const float* __restrict__ w3,
                                bf16* __restrict__ out)
{
  const float* in = blockIdx.z==0?w0 : blockIdx.z==1?w1 : blockIdx.z==2?w2 : w3;
  bf16* o = out + (size_t)blockIdx.z*768*768;
  __shared__ float tile[32][33];
  int bc = blockIdx.x*32, br = blockIdx.y*32;
  int tx = threadIdx.x, ty = threadIdx.y;
  #pragma unroll
  for (int i=ty;i<32;i+=8)
    tile[i][tx] = in[(size_t)(br+i)*768 + bc+tx];
  __syncthreads();
  #pragma unroll
  for (int i=ty;i<32;i+=8)
    o[(size_t)(bc+i)*768 + br+tx] = f2b(tile[tx][i]);
}

// X fp32 [ROWS][HID] -> bf16 (4 elems/thread)
__global__ __launch_bounds__(256)
void castX(const float* __restrict__ in, bf16* __restrict__ out)
{
  int i = blockIdx.x*256 + threadIdx.x;
  float4 f = ((const float4*)in)[i];
  union{ unsigned long long u; __bf16 h[4]; } pk;
  pk.h[0]=(__bf16)f.x; pk.h[1]=(__bf16)f.y; pk.h[2]=(__bf16)f.z; pk.h[3]=(__bf16)f.w;
  ((unsigned long long*)out)[i] = pk.u;
}

// concat bq|bk|bv -> bqkv[2304]
__global__ void concat_bias(const float* __restrict__ a, const float* __restrict__ b,
                            const float* __restrict__ c, float* __restrict__ o)
{
  int i = blockIdx.x*256 + threadIdx.x;
  if (i < 768) o[i] = a[i];
  else if (i < 1536) o[i] = b[i-768];
  else if (i < 2304) o[i] = c[i-1536];
}

// V part of qkv [row][2304] -> Vt [z=(b,h)][d][s]
__global__ void vtrans(const bf16* __restrict__ v, bf16* __restrict__ vt)
{
  int z = blockIdx.z; int b = z/NHEAD, h = z - b*NHEAD;
  int d0 = blockIdx.x*32, s0 = blockIdx.y*32;
  __shared__ bf16 t[32][33];
  int tx = threadIdx.x, ty = threadIdx.y;
  #pragma unroll
  for (int i=ty;i<32;i+=8)
    t[i][tx] = v[(size_t)(b*SEQ + s0+i)*QKVW + h*HDIM + d0+tx];
  __syncthreads();
  #pragma unroll
  for (int i=ty;i<32;i+=8)
    vt[(size_t)z*HDIM*SEQ + (size_t)(d0+i)*SEQ + s0+tx] = t[tx][i];
}

// ---------------------------------------------------------------------------
// softmax over 512 keys (scale 1/8 + additive fp32 mask), in-place
// grid: (QCH, B*NH); 2 contiguous elems/thread
// ---------------------------------------------------------------------------
__global__ __launch_bounds__(256)
void softmax512(bf16* __restrict__ sc, const float* __restrict__ mask)
{
  int z = blockIdx.y; int b = z / NHEAD;
  bf16* row = sc + ((size_t)z*QCH + blockIdx.x)*SEQ;
  int t = threadIdx.x;
  ushort2 u = ((const ushort2*)row)[t];
  float2 mk = ((const float2*)(mask + (size_t)b*SEQ))[t];
  float v0 = us2f(u.x)*0.125f + mk.x;
  float v1 = us2f(u.y)*0.125f + mk.y;
  float m = fmaxf(v0, v1);
  #pragma unroll
  for (int off=32; off; off>>=1) m = fmaxf(m, __shfl_xor(m, off));
  __shared__ float redm[4], reds[4];
  int wv = t>>6, ln = t&63;
  if (ln==0) redm[wv] = m;
  __syncthreads();
  m = fmaxf(fmaxf(redm[0],redm[1]), fmaxf(redm[2],redm[3]));
  float e0 = __expf(v0-m), e1 = __expf(v1-m);
  float s = e0+e1;
  #pragma unroll
  for (int off=32; off; off>>=1) s += __shfl_xor(s, off);
  if (ln==0) reds[wv] = s;
  __syncthreads();
  s = reds[0]+reds[1]+reds[2]+reds[3];
  float inv = 1.0f/s;
  union{ ushort2 u2; bf16 h[2]; } o;
  o.h[0] = f2b(e0*inv); o.h[1] = f2b(e1*inv);
  ((ushort2*)row)[t] = o.u2;
}

// ---------------------------------------------------------------------------
// LayerNorm over 768 cols, one block per row. In-place-safe.
// ---------------------------------------------------------------------------
template<typename TO>
__global__ __launch_bounds__(256)
void ln768(const bf16* __restrict__ y, const float* __restrict__ g,
           const float* __restrict__ be, TO* __restrict__ dst)
{
  size_t row = blockIdx.x;
  const bf16* yr = y + row*HID;
  int t = threadIdx.x;
  float x0 = b2f(yr[t]), x1 = b2f(yr[t+256]), x2 = b2f(yr[t+512]);
  float s = x0+x1+x2, q = x0*x0+x1*x1+x2*x2;
  #pragma unroll
  for (int off=32; off; off>>=1){ s += __shfl_xor(s, off); q += __shfl_xor(q, off); }
  __shared__ float rs[4], rq[4];
  int wv = t>>6;
  if ((t&63)==0){ rs[wv]=s; rq[wv]=q; }
  __syncthreads();
  s = rs[0]+rs[1]+rs[2]+rs[3];
  q = rq[0]+rq[1]+rq[2]+rq[3];
  float mean = s*(1.0f/HID);
  float var  = q*(1.0f/HID) - mean*mean;
  float inv  = rsqrtf(var + 1e-12f);
  TO* dr = dst + row*HID;
  stf(dr, t,     (x0-mean)*inv*g[t    ] + be[t    ]);
  stf(dr, t+256, (x1-mean)*inv*g[t+256] + be[t+256]);
  stf(dr, t+512, (x2-mean)*inv*g[t+512] + be[t+512]);
}

// ---------------------------------------------------------------------------
// Dialog (CLS) block: 32 rows total
// ---------------------------------------------------------------------------
__global__ __launch_bounds__(256)
void cls_proj(const bf16* __restrict__ x2,
              const float* __restrict__ Wq, const float* __restrict__ bq,
              const float* __restrict__ Wk, const float* __restrict__ bk,
              const float* __restrict__ Wv, const float* __restrict__ bv,
              bf16* __restrict__ oq, bf16* __restrict__ ok, bf16* __restrict__ ov)
{
  int mat = blockIdx.x, row = blockIdx.y;
  const float* W  = mat==0 ? Wq : (mat==1 ? Wk : Wv);
  const float* bi = mat==0 ? bq : (mat==1 ? bk : bv);
  bf16* out       = mat==0 ? oq : (mat==1 ? ok : ov);
  __shared__ float a[HID];
  const bf16* xr = x2 + (size_t)row*SEQ*HID;
  for (int i=threadIdx.x;i<HID;i+=256) a[i] = b2f(xr[i]);
  __syncthreads();
  for (int c0=0;c0<HID;c0+=256){
    int col = c0 + threadIdx.x;
    float acc = 0.f;
    for (int k=0;k<HID;k++) acc += a[k]*W[(size_t)k*HID + col];
    out[(size_t)row*HID + col] = f2b(acc + bi[col]);
  }
}

__global__ __launch_bounds__(64)
void cls_attn(const bf16* __restrict__ q, const bf16* __restrict__ k,
              const bf16* __restrict__ v, bf16* __restrict__ ctx)
{
  int z = blockIdx.x; int bb = z/NHEAD, h = z - bb*NHEAD;
  __shared__ float P[8][8];
  int t = threadIdx.x;
  int qi = t>>3, ki = t&7;
  float s = 0.f;
  for (int d=0; d<HDIM; d++)
    s += b2f(q[(size_t)(bb*8+qi)*HID + h*HDIM + d]) *
         b2f(k[(size_t)(bb*8+ki)*HID + h*HDIM + d]);
  s = s*0.125f + (ki >= qi ? -10000.0f : 0.0f);
  float m = s;
  #pragma unroll
  for (int off=4; off; off>>=1) m = fmaxf(m, __shfl_xor(m, off, 8));
  float e = __expf(s - m);
  float sum = e;
  #pragma unroll
  for (int off=4; off; off>>=1) sum += __shfl_xor(sum, off, 8);
  P[qi][ki] = e/sum;
  __syncthreads();
  for (int q2=0; q2<8; q2++){
    float acc = 0.f;
    #pragma unroll
    for (int k2=0; k2<8; k2++)
      acc += P[q2][k2] * b2f(v[(size_t)(bb*8+k2)*HID + h*HDIM + t]);
    ctx[(size_t)(bb*8+q2)*HID + h*HDIM + t] = f2b(acc);
  }
}

__global__ __launch_bounds__(256)
void cls_out(const bf16* __restrict__ ctx, const float* __restrict__ Wo,
             const float* __restrict__ bo, const float* __restrict__ g,
             const float* __restrict__ be, bf16* __restrict__ x2)
{
  int row = blockIdx.x;
  __shared__ float a[HID];
  __shared__ float yrow[HID];
  const bf16* cr = ctx + (size_t)row*HID;
  bf16* xr = x2 + (size_t)row*SEQ*HID;
  for (int i=threadIdx.x;i<HID;i+=256) a[i] = b2f(cr[i]);
  __syncthreads();
  for (int c0=0;c0<HID;c0+=256){
    int col = c0 + threadIdx.x;
    float acc = 0.f;
    for (int k=0;k<HID;k++) acc += a[k]*Wo[(size_t)k*HID + col];
    yrow[col] = acc + bo[col] + b2f(xr[col]);
  }
  __syncthreads();
  int t = threadIdx.x;
  float x0 = yrow[t], x1 = yrow[t+256], x2v = yrow[t+512];
  float s = x0+x1+x2v, qq = x0*x0+x1*x1+x2v*x2v;
  #pragma unroll
  for (int off=32; off; off>>=1){ s += __shfl_xor(s, off); qq += __shfl_xor(qq, off); }
  __shared__ float rs[4], rq[4];
  int wv = t>>6;
  if ((t&63)==0){ rs[wv]=s; rq[wv]=qq; }
  __syncthreads();
  s = rs[0]+rs[1]+rs[2]+rs[3];
  qq = rq[0]+rq[1]+rq[2]+rq[3];
  float mean = s*(1.0f/HID);
  float var  = qq*(1.0f/HID) - mean*mean;
  float inv  = rsqrtf(var + 1e-12f);
  xr[t    ] = f2b((x0 -mean)*inv*g[t    ] + be[t    ]);
  xr[t+256] = f2b((x1 -mean)*inv*g[t+256] + be[t+256]);
  xr[t+512] = f2b((x2v-mean)*inv*g[t+512] + be[t+512]);
}

// ---------------------------------------------------------------------------
extern "C" void kernel_launch(void* const* d_in, const int* in_sizes, int n_in,
                              void* d_out, int out_size, void* d_ws, size_t ws_size,
                              hipStream_t stream)
{
  const float* X    = (const float*)d_in[0];
  const float* AM   = (const float*)d_in[1];
  const float* Wq   = (const float*)d_in[2];  const float* bq  = (const float*)d_in[3];
  const float* Wk   = (const float*)d_in[4];  const float* bk  = (const float*)d_in[5];
  const float* Wv   = (const float*)d_in[6];  const float* bv  = (const float*)d_in[7];
  const float* Wao  = (const float*)d_in[8];  const float* bao = (const float*)d_in[9];
  const float* ln1g = (const float*)d_in[10]; const float* ln1b= (const float*)d_in[11];
  const float* dWq  = (const float*)d_in[12]; const float* dbq = (const float*)d_in[13];
  const float* dWk  = (const float*)d_in[14]; const float* dbk = (const float*)d_in[15];
  const float* dWv  = (const float*)d_in[16]; const float* dbv = (const float*)d_in[17];
  const float* dWo  = (const float*)d_in[18]; const float* dbo = (const float*)d_in[19];
  const float* dlng = (const float*)d_in[20]; const float* dlnb= (const float*)d_in[21];
  const float* Wi   = (const float*)d_in[22]; const float* bi  = (const float*)d_in[23];
  const float* Wo2  = (const float*)d_in[24]; const float* bo2 = (const float*)d_in[25];
  const float* ln2g = (const float*)d_in[26]; const float* ln2b= (const float*)d_in[27];
  float* OUT = (float*)d_out;

  // workspace (bf16 slabs, 256B-aligned). Peak ≈ 191 MiB (same as round 2).
  char* wp = (char*)d_ws;
  auto alloc = [&](size_t elems)->bf16*{
    bf16* p = (bf16*)wp;
    wp += ((elems*sizeof(bf16) + 255)/256)*256;
    return p;
  };
  bf16* wtq  = alloc(768*768);       // } wtq..wtv contiguous => fused QKV B
  bf16* wtk  = alloc(768*768);
  bf16* wtv  = alloc(768*768);
  bf16* wtao = alloc(768*768);
  bf16* wti  = alloc((size_t)768*3072);
  bf16* wto2 = alloc((size_t)3072*768);
  float* bqkv = (float*)alloc(2304*2);            // 2304 floats
  bf16* qkv  = alloc((size_t)ROWS*QKVW);          // } qkv+vtb contiguous:
  bf16* vtb  = alloc((size_t)ROWS*HID);           // } inter aliases both
  bf16* inter = qkv;                              //   (ROWS x 3072)
  bf16* scb  = alloc((size_t)BATCH*NHEAD*QCH*SEQ); // 48 MiB slab: sc/y/x2
  bf16* yb   = scb;
  bf16* x2   = scb;
  bf16* ctxb = alloc((size_t)ROWS*HID);
  bf16* xb   = ctxb;   // bf16 X, dead before ctx GEMM writes ctxb
  bf16* clsq = alloc(32*HID);
  bf16* clsk = alloc(32*HID);
  bf16* clsv = alloc(32*HID);
  bf16* clsc = alloc(32*HID);

  dim3 T32(32,8);
  transpose_cast4<<<dim3(24,24,4), T32, 0, stream>>>(Wq, Wk, Wv, Wao, wtq);
  transpose_cast<<<dim3(96,24), T32, 0, stream>>>(Wi,  wti, 768, 3072);
  transpose_cast<<<dim3(24,96), T32, 0, stream>>>(Wo2, wto2,3072, 768);
  concat_bias<<<9,256,0,stream>>>(bq, bk, bv, bqkv);
  castX<<<ROWS*HID/4/256,256,0,stream>>>(X, xb);

  // fused QKV projection: [16384,768] @ [768,2304] -> qkv[row][2304]
  gemm_bt<128,128,64,64,0,float><<<dim3(18,128,1),256,0,stream>>>(
      xb,768,0,0,  wtq,768,0,0,  qkv,QKVW,0,0,  768,1, bqkv, nullptr,0);

  vtrans<<<dim3(2,16,BATCH*NHEAD), T32, 0, stream>>>(qkv + 1536, vtb);

  // attention in 4 q-chunks of 128 rows
  for (int c=0;c<NCHUNK;c++){
    gemm_bt<128,128,64,64,0,float><<<dim3(4,1,BATCH*NHEAD),256,0,stream>>>(
        qkv + (size_t)c*QCH*QKVW, QKVW, (long long)SEQ*QKVW, HDIM,
        qkv + 768,                QKVW, (long long)SEQ*QKVW, HDIM,
        scb, SEQ, (long long)NHEAD*QCH*SEQ, (long long)QCH*SEQ,
        HDIM, NHEAD, nullptr, nullptr, 0);
    softmax512<<<dim3(QCH, BATCH*NHEAD),256,0,stream>>>(scb, AM);
    gemm_bt<128,64,32,64,0,float><<<dim3(1,1,BATCH*NHEAD),256,0,stream>>>(
        scb, SEQ, (long long)NHEAD*QCH*SEQ, (long long)QCH*SEQ,
        vtb, SEQ, (long long)NHEAD*HDIM*SEQ, (long long)HDIM*SEQ,
        ctxb + (size_t)c*QCH*HID, HID, (long long)SEQ*HID, HDIM,
        SEQ, NHEAD, nullptr, nullptr, 0);
  }

  // attn out-proj + bias + residual(X fp32) -> yb ; LN1 in place -> x2
  gemm_bt<128,128,64,64,2,float><<<dim3(6,128,1),256,0,stream>>>(
      ctxb,768,0,0,  wtao,768,0,0,  yb,768,0,0,  768,1, bao, X, 768);
  ln768<bf16><<<ROWS,256,0,stream>>>(yb, ln1g, ln1b, x2);

  // dialog (CLS) block on 32 rows
  cls_proj<<<dim3(3,32),256,0,stream>>>(x2, dWq,dbq, dWk,dbk, dWv,dbv,
                                        clsq, clsk, clsv);
  cls_attn<<<48,64,0,stream>>>(clsq, clsk, clsv, clsc);
  cls_out<<<32,256,0,stream>>>(clsc, dWo, dbo, dlng, dlnb, x2);

  // FFN1: inter = gelu(x2 @ Wi + bi)
  gemm_bt<128,128,64,64,1,float><<<dim3(24,128,1),256,0,stream>>>(
      x2,768,0,0,  wti,768,0,0,  inter,3072,0,0,  768,1, bi, nullptr,0);
  // FFN2: y = inter @ Wo2 + bo2 + x2 (same slab, elementwise read-before-write)
  gemm_bt<128,128,64,64,2,bf16><<<dim3(6,128,1),256,0,stream>>>(
      inter,3072,0,0,  wto2,3072,0,0,  yb,768,0,0,  3072,1, bo2, x2, 768);
  ln768<float><<<ROWS,256,0,stream>>>(yb, ln2g, ln2b, OUT);
}

// Round 5
// 995.646 us; speedup vs baseline: 1.2526x; 1.1934x over previous
//
#include <hip/hip_runtime.h>
#include <hip/hip_bf16.h>
#include <math.h>

using bf16 = __hip_bfloat16;
typedef __attribute__((ext_vector_type(8))) __bf16 bf16x8;
typedef __attribute__((ext_vector_type(4))) float f32x4;

__device__ __forceinline__ float b2f(bf16 x){ return __bfloat162float(x); }
__device__ __forceinline__ bf16  f2b(float x){ return __float2bfloat16(x); }
__device__ __forceinline__ float ldf(const float* p, size_t i){ return p[i]; }
__device__ __forceinline__ float ldf(const bf16*  p, size_t i){ return b2f(p[i]); }
__device__ __forceinline__ void stf(float* p, size_t i, float v){ p[i] = v; }
__device__ __forceinline__ void stf(bf16*  p, size_t i, float v){ p[i] = f2b(v); }

// fast gelu: tanh form, |err| ~1e-3 (fine: threshold margin 0.046 at round 3)
__device__ __forceinline__ float gelu_f(float v){
  float u = v*(0.7978845608f + 0.0356774081f*v*v);
  float e = __expf(2.f*u);
  float t = 1.f - 2.f/(e+1.f);          // tanh(u); saturates correctly at +-inf
  return 0.5f*v*(1.f+t);
}

// async 16B global->LDS (wave-uniform LDS base + lane*16)
typedef const __attribute__((address_space(1))) unsigned int* gas_u32p;
typedef __attribute__((address_space(3))) unsigned int* las_u32p;
__device__ __forceinline__ void gl_lds16(const bf16* g, bf16* l){
  __builtin_amdgcn_global_load_lds((gas_u32p)(const void*)g, (las_u32p)(void*)l, 16, 0, 0);
}

#define NHEAD 12
#define HDIM  64
#define HID   768
#define SEQ   512
#define BATCH 32
#define ROWS  (BATCH*SEQ)   // 16384
#define QKVW  2304          // packed qkv row width
#define QCH   128           // q-chunk rows for attention
#define NCHUNK (SEQ/QCH)    // 4
#define FT    128           // flash key tile

// ---------------------------------------------------------------------------
// MFMA GEMM: C[M,N] = A[M,K] * Bt[N,K]^T (+bias +epilogue), batched over
// blockIdx.z (z1=z/zdiv, z2=z%zdiv). All operands bf16; fp32 accumulate.
// Staging via global_load_lds(16B) with XOR bank swizzle.
// EPI: 0=bias, 1=bias+gelu, 2=bias+residual.
// ---------------------------------------------------------------------------
template<int BM,int BN,int WM,int WN,int EPI,typename TR>
__global__ __launch_bounds__(256)
void gemm_bt(const bf16* __restrict__ A, int lda, long long sA1, long long sA2,
             const bf16* __restrict__ Bt, int ldb, long long sB1, long long sB2,
             bf16* __restrict__ C, int ldc, long long sC1, long long sC2,
             int K, int zdiv,
             const float* __restrict__ bias,
             const TR* __restrict__ res, int ldres)
{
  constexpr int BK = 32;
  constexpr int WCOLS = BN / WN;
  constexpr int MT = WM/16, NT = WN/16;
  const int z = blockIdx.z;
  const int z1 = z / zdiv, z2 = z - z1*zdiv;
  A  += (long long)z1*sA1 + (long long)z2*sA2;
  Bt += (long long)z1*sB1 + (long long)z2*sB2;
  C  += (long long)z1*sC1 + (long long)z2*sC2;

  const int m0 = blockIdx.y*BM, n0 = blockIdx.x*BN;
  __shared__ __align__(16) bf16 As[BM*BK];
  __shared__ __align__(16) bf16 Bs[BN*BK];

  const int tid  = threadIdx.x;
  const int wave = tid>>6, lane = tid&63;
  const int r = lane&15, qd = lane>>4;
  const int wr = wave / WCOLS, wc = wave - wr*WCOLS;
  const int kcol = (qd ^ ((r>>1)&3)) * 8;   // swizzled k-column for LDS reads

  f32x4 acc[MT][NT] = {};

  constexpr int ACH = BM*BK/8;
  constexpr int BCH = BN*BK/8;

  for (int k0=0;k0<K;k0+=BK){
    #pragma unroll
    for (int c0=0;c0<ACH;c0+=256){
      int c = c0 + tid;
      int row = c>>2;
      int kc  = (c&3) ^ ((c>>3)&3);
      gl_lds16(A + (size_t)(m0+row)*lda + k0 + kc*8,
               As + ((size_t)c0 + (size_t)wave*64)*8);
    }
    #pragma unroll
    for (int c0=0;c0<BCH;c0+=256){
      int c = c0 + tid;
      int row = c>>2;
      int kc  = (c&3) ^ ((c>>3)&3);
      gl_lds16(Bt + (size_t)(n0+row)*ldb + k0 + kc*8,
               Bs + ((size_t)c0 + (size_t)wave*64)*8);
    }
    __syncthreads();
    bf16x8 af[MT]; bf16x8 bfr[NT];
    #pragma unroll
    for (int mi=0;mi<MT;mi++)
      af[mi] = *(const bf16x8*)(As + (wr*WM + mi*16 + r)*BK + kcol);
    #pragma unroll
    for (int ni=0;ni<NT;ni++)
      bfr[ni] = *(const bf16x8*)(Bs + (wc*WN + ni*16 + r)*BK + kcol);
    #pragma unroll
    for (int mi=0;mi<MT;mi++)
      #pragma unroll
      for (int ni=0;ni<NT;ni++)
        acc[mi][ni] = __builtin_amdgcn_mfma_f32_16x16x32_bf16(af[mi], bfr[ni], acc[mi][ni], 0,0,0);
    __syncthreads();
  }

  #pragma unroll
  for (int mi=0;mi<MT;mi++){
    #pragma unroll
    for (int ni=0;ni<NT;ni++){
      #pragma unroll
      for (int i=0;i<4;i++){
        int mm = m0 + wr*WM + mi*16 + qd*4 + i;   // C/D: row=(lane>>4)*4+i
        int nn = n0 + wc*WN + ni*16 + r;          //      col=lane&15
        float v = acc[mi][ni][i];
        if (bias) v += bias[nn];
        if (EPI==1) v = gelu_f(v);
        if (EPI==2) v += ldf(res, (size_t)mm*ldres + nn);
        C[(size_t)mm*ldc + nn] = f2b(v);
      }
    }
  }
}

// ---------------------------------------------------------------------------
// Fused flash attention: one block = one (b,h) x 128-row q-chunk.
// LDS: Qs 16K + Ks 16K (P tile aliases Ks) + Vts 16K + mask = 48.5 KB.
// Online softmax in registers; P relayout C->A via LDS roundtrip (2 halves).
// ---------------------------------------------------------------------------
__global__ __launch_bounds__(256)
void flash_attn(const bf16* __restrict__ qkv, const bf16* __restrict__ vtb,
                const float* __restrict__ mask, bf16* __restrict__ ctx)
{
  const int qc = blockIdx.x;
  const int z  = blockIdx.y;
  const int b  = z / NHEAD, h = z - b*NHEAD;
  const int q0 = qc*QCH;

  __shared__ __align__(16) bf16 Qs[QCH*64];
  __shared__ __align__(16) bf16 Ks[FT*64];    // aliased by P halves
  __shared__ __align__(16) bf16 Vts[64*FT];
  __shared__ float smask[FT];
  bf16* Ps = Ks;

  const int tid = threadIdx.x;
  const int wave = tid>>6, lane = tid&63;
  const int r = lane&15, qd = lane>>4;
  const int wr = wave;                        // wave owns q-rows wr*32..+32

  const bf16* Qg = qkv + ((size_t)(b*SEQ + q0))*QKVW + h*HDIM;
  const bf16* Kg = qkv + ((size_t)b*SEQ)*QKVW + 768 + h*HDIM;
  const bf16* Vg = vtb + (size_t)z*HDIM*SEQ;

  // stage Q (128 rows x 8 chunks), source-permuted for bank swizzle
  for (int c0=0;c0<1024;c0+=256){
    int c = c0+tid, row = c>>3, pos = c&7;
    gl_lds16(Qg + (size_t)row*QKVW + ((pos^(row&7))*8),
             Qs + (size_t)(c0 + wave*64)*8);
  }

  f32x4 accO[2][4] = {};             // rows wr*32+mi*16+qd*4+i ; col d=ni*16+r
  float mrun[2][4], lrun[2][4];
  #pragma unroll
  for (int a=0;a<2;a++)
    #pragma unroll
    for (int i2=0;i2<4;i2++){ mrun[a][i2]=-1e30f; lrun[a][i2]=0.f; }

  for (int k0=0; k0<SEQ; k0+=FT){
    __syncthreads();   // prior tile (or Q stage) fully consumed/landed
    for (int c0=0;c0<1024;c0+=256){            // K tile 128 x 8 chunks
      int c = c0+tid, row = c>>3, pos = c&7;
      gl_lds16(Kg + (size_t)(k0+row)*QKVW + ((pos^(row&7))*8),
               Ks + (size_t)(c0 + wave*64)*8);
    }
    for (int c0=0;c0<1024;c0+=256){            // Vt tile 64 x 16 chunks
      int c = c0+tid, row = c>>4, pos = c&15;
      gl_lds16(Vg + (size_t)row*SEQ + k0 + ((pos^(row&7))*8),
               Vts + (size_t)(c0 + wave*64)*8);
    }
    if (tid < FT) smask[tid] = mask[(size_t)b*SEQ + k0 + tid];
    __syncthreads();

    // S = Q K^T : this wave M=32, N=128, K=64
    f32x4 accS[2][8] = {};
    #pragma unroll
    for (int ks=0; ks<2; ks++){
      bf16x8 af[2], bfv[8];
      #pragma unroll
      for (int mi=0;mi<2;mi++){
        int row = wr*32 + mi*16 + r;
        int jr = ks*4 + qd;
        af[mi] = *(const bf16x8*)(Qs + row*64 + ((jr^(row&7))*8));
      }
      #pragma unroll
      for (int ni=0;ni<8;ni++){
        int row = ni*16 + r;
        int jr = ks*4 + qd;
        bfv[ni] = *(const bf16x8*)(Ks + row*64 + ((jr^(row&7))*8));
      }
      #pragma unroll
      for (int mi=0;mi<2;mi++)
        #pragma unroll
        for (int ni=0;ni<8;ni++)
          accS[mi][ni] = __builtin_amdgcn_mfma_f32_16x16x32_bf16(af[mi], bfv[ni], accS[mi][ni], 0,0,0);
    }

    // scale + mask, online-softmax update (row stats via shfl over r lanes)
    #pragma unroll
    for (int mi=0;mi<2;mi++){
      #pragma unroll
      for (int i=0;i<4;i++){
        float mx = -1e30f;
        #pragma unroll
        for (int ni=0;ni<8;ni++){
          float v = accS[mi][ni][i]*0.125f + smask[ni*16+r];
          accS[mi][ni][i] = v;
          mx = fmaxf(mx, v);
        }
        #pragma unroll
        for (int off=1; off<16; off<<=1) mx = fmaxf(mx, __shfl_xor(mx, off));
        float mnew = fmaxf(mrun[mi][i], mx);
        float alpha = __expf(mrun[mi][i] - mnew);
        mrun[mi][i] = mnew;
        float ssum = 0.f;
        #pragma unroll
        for (int ni=0;ni<8;ni++){
          float p = __expf(accS[mi][ni][i] - mnew);
          accS[mi][ni][i] = p;
          ssum += p;
        }
        #pragma unroll
        for (int off=1; off<16; off<<=1) ssum += __shfl_xor(ssum, off);
        lrun[mi][i] = lrun[mi][i]*alpha + ssum;
        #pragma unroll
        for (int ni=0;ni<4;ni++) accO[mi][ni][i] *= alpha;
      }
    }

    // P (C-layout regs) -> LDS (A-layout reads), two 64-key halves over Ks
    #pragma unroll
    for (int half=0; half<2; half++){
      __syncthreads();   // Ks reads (half0) / PV reads (half1) complete
      #pragma unroll
      for (int mi=0;mi<2;mi++){
        #pragma unroll
        for (int i=0;i<4;i++){
          int row = wr*32 + mi*16 + qd*4 + i;
          #pragma unroll
          for (int nj=0;nj<4;nj++){
            int colL = nj*16 + r;
            int chunk = colL>>3;
            Ps[row*64 + ((chunk^(row&7))*8) + (colL&7)] = f2b(accS[mi][half*4+nj][i]);
          }
        }
      }
      __syncthreads();
      #pragma unroll
      for (int ks=0; ks<2; ks++){
        bf16x8 af[2], bfv[4];
        #pragma unroll
        for (int mi=0;mi<2;mi++){
          int row = wr*32 + mi*16 + r;
          int jr = ks*4 + qd;
          af[mi] = *(const bf16x8*)(Ps + row*64 + ((jr^(row&7))*8));
        }
        #pragma unroll
        for (int ni=0;ni<4;ni++){
          int row = ni*16 + r;
          int jrv = half*8 + ks*4 + qd;
          bfv[ni] = *(const bf16x8*)(Vts + row*FT + ((jrv^(row&7))*8));
        }
        #pragma unroll
        for (int mi=0;mi<2;mi++)
          #pragma unroll
          for (int ni=0;ni<4;ni++)
            accO[mi][ni] = __builtin_amdgcn_mfma_f32_16x16x32_bf16(af[mi], bfv[ni], accO[mi][ni], 0,0,0);
      }
    }
  }

  bf16* Cg = ctx + ((size_t)(b*SEQ + q0))*HID + h*HDIM;
  #pragma unroll
  for (int mi=0;mi<2;mi++)
    #pragma unroll
    for (int i=0;i<4;i++){
      int row = wr*32 + mi*16 + qd*4 + i;
      float invl = 1.0f/lrun[mi][i];
      #pragma unroll
      for (int ni=0;ni<4;ni++)
        Cg[(size_t)row*HID + ni*16 + r] = f2b(accO[mi][ni][i]*invl);
    }
}

// ---------------------------------------------------------------------------
// Weight transpose + fp32->bf16 cast
// ---------------------------------------------------------------------------
__global__ void transpose_cast(const float* __restrict__ in, bf16* __restrict__ out,
                               int R, int C)
{
  __shared__ float tile[32][33];
  int bc = blockIdx.x*32, br = blockIdx.y*32;
  int tx = threadIdx.x, ty = threadIdx.y;
  #pragma unroll
  for (int i=ty;i<32;i+=8)
    tile[i][tx] = in[(size_t)(br+i)*C + bc+tx];
  __syncthreads();
  #pragma unroll
  for (int i=ty;i<32;i+=8)
    out[(size_t)(bc+i)*R + br+tx] = f2b(tile[tx][i]);
}

__global__ void transpose_cast4(const float* __restrict__ w0, const float* __restrict__ w1,
                                const float* __restrict__ w2, const float* __restrict__ w3,
                                bf16* __restrict__ out)
{
  const float* in = blockIdx.z==0?w0 : blockIdx.z==1?w1 : blockIdx.z==2?w2 : w3;
  bf16* o = out + (size_t)blockIdx.z*768*768;
  __shared__ float tile[32][33];
  int bc = blockIdx.x*32, br = blockIdx.y*32;
  int tx = threadIdx.x, ty = threadIdx.y;
  #pragma unroll
  for (int i=ty;i<32;i+=8)
    tile[i][tx] = in[(size_t)(br+i)*768 + bc+tx];
  __syncthreads();
  #pragma unroll
  for (int i=ty;i<32;i+=8)
    o[(size_t)(bc+i)*768 + br+tx] = f2b(tile[tx][i]);
}

__global__ __launch_bounds__(256)
void castX(const float* __restrict__ in, bf16* __restrict__ out)
{
  int i = blockIdx.x*256 + threadIdx.x;
  float4 f = ((const float4*)in)[i];
  union{ unsigned long long u; __bf16 h[4]; } pk;
  pk.h[0]=(__bf16)f.x; pk.h[1]=(__bf16)f.y; pk.h[2]=(__bf16)f.z; pk.h[3]=(__bf16)f.w;
  ((unsigned long long*)out)[i] = pk.u;
}

__global__ void concat_bias(const float* __restrict__ a, const float* __restrict__ b,
                            const float* __restrict__ c, float* __restrict__ o)
{
  int i = blockIdx.x*256 + threadIdx.x;
  if (i < 768) o[i] = a[i];
  else if (i < 1536) o[i] = b[i-768];
  else if (i < 2304) o[i] = c[i-1536];
}

// V part of qkv [row][2304] -> Vt [z=(b,h)][d][s]
__global__ void vtrans(const bf16* __restrict__ v, bf16* __restrict__ vt)
{
  int z = blockIdx.z; int b = z/NHEAD, h = z - b*NHEAD;
  int d0 = blockIdx.x*32, s0 = blockIdx.y*32;
  __shared__ bf16 t[32][33];
  int tx = threadIdx.x, ty = threadIdx.y;
  #pragma unroll
  for (int i=ty;i<32;i+=8)
    t[i][tx] = v[(size_t)(b*SEQ + s0+i)*QKVW + h*HDIM + d0+tx];
  __syncthreads();
  #pragma unroll
  for (int i=ty;i<32;i+=8)
    vt[(size_t)z*HDIM*SEQ + (size_t)(d0+i)*SEQ + s0+tx] = t[tx][i];
}

// ---------------------------------------------------------------------------
// LayerNorm over 768 cols, one block per row. In-place-safe.
// ---------------------------------------------------------------------------
template<typename TO>
__global__ __launch_bounds__(256)
void ln768(const bf16* __restrict__ y, const float* __restrict__ g,
           const float* __restrict__ be, TO* __restrict__ dst)
{
  size_t row = blockIdx.x;
  const bf16* yr = y + row*HID;
  int t = threadIdx.x;
  float x0 = b2f(yr[t]), x1 = b2f(yr[t+256]), x2 = b2f(yr[t+512]);
  float s = x0+x1+x2, q = x0*x0+x1*x1+x2*x2;
  #pragma unroll
  for (int off=32; off; off>>=1){ s += __shfl_xor(s, off); q += __shfl_xor(q, off); }
  __shared__ float rs[4], rq[4];
  int wv = t>>6;
  if ((t&63)==0){ rs[wv]=s; rq[wv]=q; }
  __syncthreads();
  s = rs[0]+rs[1]+rs[2]+rs[3];
  q = rq[0]+rq[1]+rq[2]+rq[3];
  float mean = s*(1.0f/HID);
  float var  = q*(1.0f/HID) - mean*mean;
  float inv  = rsqrtf(var + 1e-12f);
  TO* dr = dst + row*HID;
  stf(dr, t,     (x0-mean)*inv*g[t    ] + be[t    ]);
  stf(dr, t+256, (x1-mean)*inv*g[t+256] + be[t+256]);
  stf(dr, t+512, (x2-mean)*inv*g[t+512] + be[t+512]);
}

// ---------------------------------------------------------------------------
// Dialog (CLS) block: 32 rows total
// ---------------------------------------------------------------------------
__global__ __launch_bounds__(256)
void cls_proj(const bf16* __restrict__ x2,
              const float* __restrict__ Wq, const float* __restrict__ bq,
              const float* __restrict__ Wk, const float* __restrict__ bk,
              const float* __restrict__ Wv, const float* __restrict__ bv,
              bf16* __restrict__ oq, bf16* __restrict__ ok, bf16* __restrict__ ov)
{
  int mat = blockIdx.x, row = blockIdx.y;
  const float* W  = mat==0 ? Wq : (mat==1 ? Wk : Wv);
  const float* bi = mat==0 ? bq : (mat==1 ? bk : bv);
  bf16* out       = mat==0 ? oq : (mat==1 ? ok : ov);
  __shared__ float a[HID];
  const bf16* xr = x2 + (size_t)row*SEQ*HID;
  for (int i=threadIdx.x;i<HID;i+=256) a[i] = b2f(xr[i]);
  __syncthreads();
  for (int c0=0;c0<HID;c0+=256){
    int col = c0 + threadIdx.x;
    float acc = 0.f;
    for (int k=0;k<HID;k++) acc += a[k]*W[(size_t)k*HID + col];
    out[(size_t)row*HID + col] = f2b(acc + bi[col]);
  }
}

__global__ __launch_bounds__(64)
void cls_attn(const bf16* __restrict__ q, const bf16* __restrict__ k,
              const bf16* __restrict__ v, bf16* __restrict__ ctx)
{
  int z = blockIdx.x; int bb = z/NHEAD, h = z - bb*NHEAD;
  __shared__ float P[8][8];
  int t = threadIdx.x;
  int qi = t>>3, ki = t&7;
  float s = 0.f;
  for (int d=0; d<HDIM; d++)
    s += b2f(q[(size_t)(bb*8+qi)*HID + h*HDIM + d]) *
         b2f(k[(size_t)(bb*8+ki)*HID + h*HDIM + d]);
  s = s*0.125f + (ki >= qi ? -10000.0f : 0.0f);
  float m = s;
  #pragma unroll
  for (int off=4; off; off>>=1) m = fmaxf(m, __shfl_xor(m, off, 8));
  float e = __expf(s - m);
  float sum = e;
  #pragma unroll
  for (int off=4; off; off>>=1) sum += __shfl_xor(sum, off, 8);
  P[qi][ki] = e/sum;
  __syncthreads();
  for (int q2=0; q2<8; q2++){
    float acc = 0.f;
    #pragma unroll
    for (int k2=0; k2<8; k2++)
      acc += P[q2][k2] * b2f(v[(size_t)(bb*8+k2)*HID + h*HDIM + t]);
    ctx[(size_t)(bb*8+q2)*HID + h*HDIM + t] = f2b(acc);
  }
}

__global__ __launch_bounds__(256)
void cls_out(const bf16* __restrict__ ctx, const float* __restrict__ Wo,
             const float* __restrict__ bo, const float* __restrict__ g,
             const float* __restrict__ be, bf16* __restrict__ x2)
{
  int row = blockIdx.x;
  __shared__ float a[HID];
  __shared__ float yrow[HID];
  const bf16* cr = ctx + (size_t)row*HID;
  bf16* xr = x2 + (size_t)row*SEQ*HID;
  for (int i=threadIdx.x;i<HID;i+=256) a[i] = b2f(cr[i]);
  __syncthreads();
  for (int c0=0;c0<HID;c0+=256){
    int col = c0 + threadIdx.x;
    float acc = 0.f;
    for (int k=0;k<HID;k++) acc += a[k]*Wo[(size_t)k*HID + col];
    yrow[col] = acc + bo[col] + b2f(xr[col]);
  }
  __syncthreads();
  int t = threadIdx.x;
  float x0 = yrow[t], x1 = yrow[t+256], x2v = yrow[t+512];
  float s = x0+x1+x2v, qq = x0*x0+x1*x1+x2v*x2v;
  #pragma unroll
  for (int off=32; off; off>>=1){ s += __shfl_xor(s, off); qq += __shfl_xor(qq, off); }
  __shared__ float rs[4], rq[4];
  int wv = t>>6;
  if ((t&63)==0){ rs[wv]=s; rq[wv]=qq; }
  __syncthreads();
  s = rs[0]+rs[1]+rs[2]+rs[3];
  qq = rq[0]+rq[1]+rq[2]+rq[3];
  float mean = s*(1.0f/HID);
  float var  = qq*(1.0f/HID) - mean*mean;
  float inv  = rsqrtf(var + 1e-12f);
  xr[t    ] = f2b((x0 -mean)*inv*g[t    ] + be[t    ]);
  xr[t+256] = f2b((x1 -mean)*inv*g[t+256] + be[t+256]);
  xr[t+512] = f2b((x2v-mean)*inv*g[t+512] + be[t+512]);
}

// ---------------------------------------------------------------------------
extern "C" void kernel_launch(void* const* d_in, const int* in_sizes, int n_in,
                              void* d_out, int out_size, void* d_ws, size_t ws_size,
                              hipStream_t stream)
{
  const float* X    = (const float*)d_in[0];
  const float* AM   = (const float*)d_in[1];
  const float* Wq   = (const float*)d_in[2];  const float* bq  = (const float*)d_in[3];
  const float* Wk   = (const float*)d_in[4];  const float* bk  = (const float*)d_in[5];
  const float* Wv   = (const float*)d_in[6];  const float* bv  = (const float*)d_in[7];
  const float* Wao  = (const float*)d_in[8];  const float* bao = (const float*)d_in[9];
  const float* ln1g = (const float*)d_in[10]; const float* ln1b= (const float*)d_in[11];
  const float* dWq  = (const float*)d_in[12]; const float* dbq = (const float*)d_in[13];
  const float* dWk  = (const float*)d_in[14]; const float* dbk = (const float*)d_in[15];
  const float* dWv  = (const float*)d_in[16]; const float* dbv = (const float*)d_in[17];
  const float* dWo  = (const float*)d_in[18]; const float* dbo = (const float*)d_in[19];
  const float* dlng = (const float*)d_in[20]; const float* dlnb= (const float*)d_in[21];
  const float* Wi   = (const float*)d_in[22]; const float* bi  = (const float*)d_in[23];
  const float* Wo2  = (const float*)d_in[24]; const float* bo2 = (const float*)d_in[25];
  const float* ln2g = (const float*)d_in[26]; const float* ln2b= (const float*)d_in[27];
  float* OUT = (float*)d_out;

  char* wp = (char*)d_ws;
  auto alloc = [&](size_t elems)->bf16*{
    bf16* p = (bf16*)wp;
    wp += ((elems*sizeof(bf16) + 255)/256)*256;
    return p;
  };
  bf16* wtq  = alloc(768*768);       // wtq..wtv contiguous => fused QKV B
  bf16* wtk  = alloc(768*768);
  bf16* wtv  = alloc(768*768);
  bf16* wtao = alloc(768*768);
  bf16* wti  = alloc((size_t)768*3072);
  bf16* wto2 = alloc((size_t)3072*768);
  float* bqkv = (float*)alloc(2304*2);
  bf16* qkv  = alloc((size_t)ROWS*QKVW);          // } qkv+vtb contiguous:
  bf16* vtb  = alloc((size_t)ROWS*HID);           // } inter aliases both
  bf16* inter = qkv;
  bf16* scb  = alloc((size_t)ROWS*HID);            // y/x2 slab
  bf16* yb   = scb;
  bf16* x2   = scb;
  bf16* ctxb = alloc((size_t)ROWS*HID);
  bf16* xb   = ctxb;   // bf16 X, dead before flash writes ctxb
  bf16* clsq = alloc(32*HID);
  bf16* clsk = alloc(32*HID);
  bf16* clsv = alloc(32*HID);
  bf16* clsc = alloc(32*HID);
  (void)wtk; (void)wtv;

  dim3 T32(32,8);
  transpose_cast4<<<dim3(24,24,4), T32, 0, stream>>>(Wq, Wk, Wv, Wao, wtq);
  transpose_cast<<<dim3(96,24), T32, 0, stream>>>(Wi,  wti, 768, 3072);
  transpose_cast<<<dim3(24,96), T32, 0, stream>>>(Wo2, wto2,3072, 768);
  concat_bias<<<9,256,0,stream>>>(bq, bk, bv, bqkv);
  castX<<<ROWS*HID/4/256,256,0,stream>>>(X, xb);

  // fused QKV projection: [16384,768] @ [768,2304] -> qkv[row][2304]
  gemm_bt<128,128,64,64,0,float><<<dim3(18,128,1),256,0,stream>>>(
      xb,768,0,0,  wtq,768,0,0,  qkv,QKVW,0,0,  768,1, bqkv, nullptr,0);

  vtrans<<<dim3(2,16,BATCH*NHEAD), T32, 0, stream>>>(qkv + 1536, vtb);

  // fused flash attention -> ctxb
  flash_attn<<<dim3(NCHUNK, BATCH*NHEAD),256,0,stream>>>(qkv, vtb, AM, ctxb);

  // attn out-proj + bias + residual(X fp32) -> yb ; LN1 in place -> x2
  gemm_bt<128,128,64,64,2,float><<<dim3(6,128,1),256,0,stream>>>(
      ctxb,768,0,0,  wtao,768,0,0,  yb,768,0,0,  768,1, bao, X, 768);
  ln768<bf16><<<ROWS,256,0,stream>>>(yb, ln1g, ln1b, x2);

  // dialog (CLS) block on 32 rows
  cls_proj<<<dim3(3,32),256,0,stream>>>(x2, dWq,dbq, dWk,dbk, dWv,dbv,
                                        clsq, clsk, clsv);
  cls_attn<<<48,64,0,stream>>>(clsq, clsk, clsv, clsc);
  cls_out<<<32,256,0,stream>>>(clsc, dWo, dbo, dlng, dlnb, x2);

  // FFN1: inter = gelu(x2 @ Wi + bi)
  gemm_bt<128,128,64,64,1,float><<<dim3(24,128,1),256,0,stream>>>(
      x2,768,0,0,  wti,768,0,0,  inter,3072,0,0,  768,1, bi, nullptr,0);
  // FFN2: y = inter @ Wo2 + bo2 + x2
  gemm_bt<128,128,64,64,2,bf16><<<dim3(6,128,1),256,0,stream>>>(
      inter,3072,0,0,  wto2,3072,0,0,  yb,768,0,0,  3072,1, bo2, x2, 768);
  ln768<float><<<ROWS,256,0,stream>>>(yb, ln2g, ln2b, OUT);
}